// Round 3
// baseline (99.556 us; speedup 1.0000x reference)
//
#include <hip/hip_runtime.h>

#define NN 4096
#define HID 512
#define DD 64
#define SLOPE 0.2f
#define CH 256
#define CL 16   // NN/CH
#define NBLK 64 // blocks in fused kernel

__device__ inline const float* uniform_cptr(const float* p) {
  uint64_t v = (uint64_t)p;
  uint32_t lo = __builtin_amdgcn_readfirstlane((uint32_t)v);
  uint32_t hi = __builtin_amdgcn_readfirstlane((uint32_t)(v >> 32));
  return (const float*)(((uint64_t)hi << 32) | (uint64_t)lo);
}

// Device-scope grid barrier: 64 blocks are trivially co-resident on 256 CUs.
__device__ inline void gridbar(int* cnt, int gen) {
  __syncthreads();
  if (threadIdx.x == 0) {
    __threadfence();                      // release prior global writes
    atomicAdd(cnt, 1);                    // device-scope by default
    while (__hip_atomic_load(cnt, __ATOMIC_ACQUIRE, __HIP_MEMORY_SCOPE_AGENT)
           < NBLK * gen) {}
  }
  __syncthreads();
}

// ---------------- k1: xt = x@W, s1 = xt@a1, s2 = xt@a2 -----------------------
// W staged in LDS (128 KiB); x read via wave-uniform (scalar-pipe) loads.
__global__ __launch_bounds__(256) void k1_xt(
    const float* __restrict__ x, const float* __restrict__ W,
    const float* __restrict__ a,
    float* __restrict__ xt, float* __restrict__ s1, float* __restrict__ s2,
    int* __restrict__ cnt) {
  __shared__ float Wl[HID * DD];           // 128 KiB
  int tid = threadIdx.x;
  if (blockIdx.x == 0 && tid == 0) *cnt = 0;   // reset fused-kernel barrier
  const float4* W4 = (const float4*)W;
  float4* Wl4 = (float4*)Wl;
#pragma unroll
  for (int u = 0; u < (HID * DD / 4) / 256; ++u)
    Wl4[u * 256 + tid] = W4[u * 256 + tid];
  __syncthreads();
  int wave = tid >> 6, lane = tid & 63;
  int i0 = blockIdx.x * 16 + wave * 4;     // 4 rows per wave
  const float* xr = uniform_cptr(x + (size_t)i0 * HID);
  float acc0 = 0.f, acc1 = 0.f, acc2 = 0.f, acc3 = 0.f;
  for (int k0 = 0; k0 < HID; k0 += 8) {
    float xa0[8], xa1[8], xa2[8], xa3[8];
#pragma unroll
    for (int j = 0; j < 8; ++j) {
      xa0[j] = xr[0 * HID + k0 + j];
      xa1[j] = xr[1 * HID + k0 + j];
      xa2[j] = xr[2 * HID + k0 + j];
      xa3[j] = xr[3 * HID + k0 + j];
    }
#pragma unroll
    for (int j = 0; j < 8; ++j) {
      float wv = Wl[(k0 + j) * DD + lane];
      acc0 = fmaf(xa0[j], wv, acc0);
      acc1 = fmaf(xa1[j], wv, acc1);
      acc2 = fmaf(xa2[j], wv, acc2);
      acc3 = fmaf(xa3[j], wv, acc3);
    }
  }
  xt[(i0 + 0) * DD + lane] = acc0;
  xt[(i0 + 1) * DD + lane] = acc1;
  xt[(i0 + 2) * DD + lane] = acc2;
  xt[(i0 + 3) * DD + lane] = acc3;
  float a1 = a[lane], a2 = a[DD + lane];
  float p10 = acc0 * a1, p20 = acc0 * a2;
  float p11 = acc1 * a1, p21 = acc1 * a2;
  float p12 = acc2 * a1, p22 = acc2 * a2;
  float p13 = acc3 * a1, p23 = acc3 * a2;
#pragma unroll
  for (int off = 32; off >= 1; off >>= 1) {
    p10 += __shfl_xor(p10, off, 64); p20 += __shfl_xor(p20, off, 64);
    p11 += __shfl_xor(p11, off, 64); p21 += __shfl_xor(p21, off, 64);
    p12 += __shfl_xor(p12, off, 64); p22 += __shfl_xor(p22, off, 64);
    p13 += __shfl_xor(p13, off, 64); p23 += __shfl_xor(p23, off, 64);
  }
  if (lane == 0) {
    s1[i0 + 0] = p10; s2[i0 + 0] = p20;
    s1[i0 + 1] = p11; s2[i0 + 1] = p21;
    s1[i0 + 2] = p12; s2[i0 + 2] = p22;
    s1[i0 + 3] = p13; s2[i0 + 3] = p23;
  }
}

// ---------------- kC: rank -> chunk scans -> offsets -> output ---------------
// 64 blocks x 256 threads, 3 manual grid barriers.
__global__ __launch_bounds__(256) void kC_fused(
    const float* __restrict__ xt, const float* __restrict__ s1,
    const float* __restrict__ s2,
    float* __restrict__ s2s, int* __restrict__ perm,
    float* __restrict__ SP, float* __restrict__ SN,
    float* __restrict__ zP, float* __restrict__ zN,
    float* __restrict__ offP, float* __restrict__ offN,
    float* __restrict__ offZP, float* __restrict__ offZN,
    int* cnt, float* __restrict__ out) {
  __shared__ float keys[NN];     // 16 KiB: unsorted s2, later sorted s2s
  __shared__ int pc[4][64];
  int tid = threadIdx.x, w = tid >> 6, l = tid & 63, b = blockIdx.x;

  // P0: stage unsorted keys
  {
    const float4* s4 = (const float4*)s2;
    float4* kk = (float4*)keys;
#pragma unroll
    for (int u = 0; u < NN / 4 / 256; ++u)
      kk[u * 256 + tid] = s4[u * 256 + tid];
  }
  __syncthreads();

  // P1: rank-by-count; lane owns element e = b*64+l, wave scans 1024-key slice
  {
    int e = b * 64 + l;
    float ke = keys[e];
    const float4* kk4 = (const float4*)keys;
    int c_ = 0;
    for (int q4 = w * 256; q4 < w * 256 + 256; ++q4) {
      float4 kv = kk4[q4];
      int q = q4 * 4;
      c_ += (kv.x < ke || (kv.x == ke && q + 0 < e)) ? 1 : 0;
      c_ += (kv.y < ke || (kv.y == ke && q + 1 < e)) ? 1 : 0;
      c_ += (kv.z < ke || (kv.z == ke && q + 2 < e)) ? 1 : 0;
      c_ += (kv.w < ke || (kv.w == ke && q + 3 < e)) ? 1 : 0;
    }
    pc[w][l] = c_;
    __syncthreads();
    if (w == 0) {
      int rank = pc[0][l] + pc[1][l] + pc[2][l] + pc[3][l];
      s2s[rank] = ke;
      perm[rank] = b * 64 + l;
    }
  }
  gridbar(cnt, 1);

  // P2: reload sorted keys
  {
    const float4* s4 = (const float4*)s2s;
    float4* kk = (float4*)keys;
#pragma unroll
    for (int u = 0; u < NN / 4 / 256; ++u)
      kk[u * 256 + tid] = s4[u * 256 + tid];
  }
  __syncthreads();

  // P3: per-wave chunk scan (chunk cw = b*4+w, CL=16 rows)
  {
    int cw = b * 4 + w, r0 = cw * CL;
    float evP[CL], evN[CL];
    int pmv[CL];
#pragma unroll
    for (int q = 0; q < CL; ++q) {
      float sv = keys[r0 + q];
      evP[q] = expf(sv);
      evN[q] = expf(SLOPE * sv);
    }
#pragma unroll
    for (int q = 0; q < CL; ++q) pmv[q] = perm[r0 + q] * DD;
    float aP = 0.f, aN = 0.f, azP = 0.f, azN = 0.f;
#pragma unroll
    for (int q = 0; q < CL; ++q) {
      float xv = xt[pmv[q] + l];
      aP = fmaf(evP[q], xv, aP);
      aN = fmaf(evN[q], xv, aN);
      azP += evP[q]; azN += evN[q];
      SP[(r0 + q) * DD + l] = aP;
      SN[(r0 + q) * DD + l] = aN;
      if (l == 0) { zP[r0 + q] = azP; zN[r0 + q] = azN; }
    }
  }
  gridbar(cnt, 2);

  // P4: block 0 computes exclusive chunk offsets (+ totals at index CH)
  if (b == 0) {
    if (w == 0) {
      float rP = 0.f, rN = 0.f;
      for (int cb = 0; cb < CH; cb += 8) {
        float vP[8], vN[8];
#pragma unroll
        for (int j = 0; j < 8; ++j) {
          int r = (cb + j) * CL + CL - 1;
          vP[j] = SP[r * DD + l];
          vN[j] = SN[r * DD + l];
        }
#pragma unroll
        for (int j = 0; j < 8; ++j) {
          offP[(cb + j) * DD + l] = rP;
          offN[(cb + j) * DD + l] = rN;
          rP += vP[j]; rN += vN[j];
        }
      }
      offP[CH * DD + l] = rP;   // totP
      offN[CH * DD + l] = rN;
    } else if (w == 1 || w == 2) {
      const float* zsrc = (w == 1) ? zP : zN;
      float* zdst = (w == 1) ? offZP : offZN;
      float v0 = zsrc[(4 * l + 0) * CL + CL - 1];
      float v1 = zsrc[(4 * l + 1) * CL + CL - 1];
      float v2 = zsrc[(4 * l + 2) * CL + CL - 1];
      float v3 = zsrc[(4 * l + 3) * CL + CL - 1];
      float p1 = v0, p2 = v0 + v1, p3 = v0 + v1 + v2;
      float T = p3 + v3;
      float incl = T;
#pragma unroll
      for (int off = 1; off < 64; off <<= 1) {
        float t = __shfl_up(incl, off, 64);
        if (l >= off) incl += t;
      }
      float excl = incl - T;
      zdst[4 * l + 0] = excl;
      zdst[4 * l + 1] = excl + p1;
      zdst[4 * l + 2] = excl + p2;
      zdst[4 * l + 3] = excl + p3;
      if (l == 63) zdst[CH] = incl;   // total
    }
  }
  gridbar(cnt, 3);

  // P5: output. Per-lane binary search in LDS, then 16 rows per wave.
  {
    float totP = offP[CH * DD + l];
    float totZ = offZP[CH];
    int q0 = l & 15;
    int i = b * 64 + w * 16 + q0;
    float s1v = s1[i];
    float t = -s1v;
    int lo = 0, hi = NN;
#pragma unroll
    for (int it = 0; it < 12; ++it) {
      int mid = (lo + hi) >> 1;
      if (keys[mid] <= t) lo = mid + 1; else hi = mid;
    }
    int kq = lo;   // split: N = [0,kq), P = [kq, NN)
#pragma unroll
    for (int q = 0; q < 16; ++q) {
      int kk_ = __shfl(kq, q, 64);
      float s1q = __shfl(s1v, q, 64);
      float wPq = expf(s1q);
      float wNq = expf(SLOPE * s1q);
      float FPk = 0.f, FNk = 0.f, ZPk = 0.f, ZNk = 0.f;
      if (kk_ > 0) {
        int r = kk_ - 1, c = r >> 4;
        FPk = offP[c * DD + l] + SP[r * DD + l];
        FNk = offN[c * DD + l] + SN[r * DD + l];
        ZPk = offZP[c] + zP[r];
        ZNk = offZN[c] + zN[r];
      }
      float num = wPq * (totP - FPk) + wNq * FNk;
      float den = wPq * (totZ - ZPk) + wNq * ZNk;
      out[(b * 64 + w * 16 + q) * DD + l] = num / den;
    }
  }
}

extern "C" void kernel_launch(void* const* d_in, const int* in_sizes, int n_in,
                              void* d_out, int out_size, void* d_ws, size_t ws_size,
                              hipStream_t stream) {
  const float* x = (const float*)d_in[0];
  const float* W = (const float*)d_in[1];
  const float* a = (const float*)d_in[2];
  float* out = (float*)d_out;

  float* ws = (float*)d_ws;
  float* xt    = ws;                   // NN*DD
  float* s1    = xt + NN * DD;         // NN
  float* s2    = s1 + NN;              // NN
  float* s2s   = s2 + NN;              // NN
  int*   perm  = (int*)(s2s + NN);     // NN
  float* SP    = (float*)(perm + NN);  // NN*DD
  float* SN    = SP + NN * DD;         // NN*DD
  float* zP    = SN + NN * DD;         // NN
  float* zN    = zP + NN;              // NN
  float* offP  = zN + NN;              // (CH+1)*DD
  float* offN  = offP + (CH + 1) * DD; // (CH+1)*DD
  float* offZP = offN + (CH + 1) * DD; // CH+1
  float* offZN = offZP + (CH + 1);     // CH+1
  int*   cnt   = (int*)(offZN + (CH + 1));

  k1_xt<<<NN / 16, 256, 0, stream>>>(x, W, a, xt, s1, s2, cnt);
  kC_fused<<<NBLK, 256, 0, stream>>>(xt, s1, s2, s2s, perm, SP, SN, zP, zN,
                                     offP, offN, offZP, offZN, cnt, out);
}

// Round 4
// 82.671 us; speedup vs baseline: 1.2042x; 1.2042x over previous
//
#include <hip/hip_runtime.h>

#define NN 4096
#define HID 512
#define DD 64
#define SLOPE 0.2f
#define CH 256
#define CL 16   // NN/CH
#define NBLK 64 // blocks in fused kernel

__device__ inline const float* uniform_cptr(const float* p) {
  uint64_t v = (uint64_t)p;
  uint32_t lo = __builtin_amdgcn_readfirstlane((uint32_t)v);
  uint32_t hi = __builtin_amdgcn_readfirstlane((uint32_t)(v >> 32));
  return (const float*)(((uint64_t)hi << 32) | (uint64_t)lo);
}

// Grid barrier with RELAXED polling (no per-poll L2 invalidate) + single
// acquire fence at the end. 64 blocks on 256 CUs -> always co-resident.
__device__ inline void gridbar(int* cnt, int gen) {
  __syncthreads();
  if (threadIdx.x == 0) {
    __builtin_amdgcn_fence(__ATOMIC_RELEASE, "agent");   // writeback once
    __hip_atomic_fetch_add(cnt, 1, __ATOMIC_RELAXED, __HIP_MEMORY_SCOPE_AGENT);
    while (__hip_atomic_load(cnt, __ATOMIC_RELAXED, __HIP_MEMORY_SCOPE_AGENT)
           < NBLK * gen)
      __builtin_amdgcn_s_sleep(4);
    __builtin_amdgcn_fence(__ATOMIC_ACQUIRE, "agent");   // invalidate once
  }
  __syncthreads();
}

// ---------------- k1: xt = x@W, s1 = xt@a1, s2 = xt@a2 -----------------------
// W staged in LDS (128 KiB); x read via wave-uniform (scalar-pipe) loads.
__global__ __launch_bounds__(256) void k1_xt(
    const float* __restrict__ x, const float* __restrict__ W,
    const float* __restrict__ a,
    float* __restrict__ xt, float* __restrict__ s1, float* __restrict__ s2,
    int* __restrict__ cnt) {
  __shared__ float Wl[HID * DD];           // 128 KiB
  int tid = threadIdx.x;
  if (blockIdx.x == 0 && tid == 0)
    __hip_atomic_store(cnt, 0, __ATOMIC_RELAXED, __HIP_MEMORY_SCOPE_AGENT);
  const float4* W4 = (const float4*)W;
  float4* Wl4 = (float4*)Wl;
#pragma unroll
  for (int u = 0; u < (HID * DD / 4) / 256; ++u)
    Wl4[u * 256 + tid] = W4[u * 256 + tid];
  __syncthreads();
  int wave = tid >> 6, lane = tid & 63;
  int i0 = blockIdx.x * 16 + wave * 4;     // 4 rows per wave
  const float* xr = uniform_cptr(x + (size_t)i0 * HID);
  float acc0 = 0.f, acc1 = 0.f, acc2 = 0.f, acc3 = 0.f;
  for (int k0 = 0; k0 < HID; k0 += 8) {
    float xa0[8], xa1[8], xa2[8], xa3[8];
#pragma unroll
    for (int j = 0; j < 8; ++j) {
      xa0[j] = xr[0 * HID + k0 + j];
      xa1[j] = xr[1 * HID + k0 + j];
      xa2[j] = xr[2 * HID + k0 + j];
      xa3[j] = xr[3 * HID + k0 + j];
    }
#pragma unroll
    for (int j = 0; j < 8; ++j) {
      float wv = Wl[(k0 + j) * DD + lane];
      acc0 = fmaf(xa0[j], wv, acc0);
      acc1 = fmaf(xa1[j], wv, acc1);
      acc2 = fmaf(xa2[j], wv, acc2);
      acc3 = fmaf(xa3[j], wv, acc3);
    }
  }
  xt[(i0 + 0) * DD + lane] = acc0;
  xt[(i0 + 1) * DD + lane] = acc1;
  xt[(i0 + 2) * DD + lane] = acc2;
  xt[(i0 + 3) * DD + lane] = acc3;
  float a1 = a[lane], a2 = a[DD + lane];
  float p10 = acc0 * a1, p20 = acc0 * a2;
  float p11 = acc1 * a1, p21 = acc1 * a2;
  float p12 = acc2 * a1, p22 = acc2 * a2;
  float p13 = acc3 * a1, p23 = acc3 * a2;
#pragma unroll
  for (int off = 32; off >= 1; off >>= 1) {
    p10 += __shfl_xor(p10, off, 64); p20 += __shfl_xor(p20, off, 64);
    p11 += __shfl_xor(p11, off, 64); p21 += __shfl_xor(p21, off, 64);
    p12 += __shfl_xor(p12, off, 64); p22 += __shfl_xor(p22, off, 64);
    p13 += __shfl_xor(p13, off, 64); p23 += __shfl_xor(p23, off, 64);
  }
  if (lane == 0) {
    s1[i0 + 0] = p10; s2[i0 + 0] = p20;
    s1[i0 + 1] = p11; s2[i0 + 1] = p21;
    s1[i0 + 2] = p12; s2[i0 + 2] = p22;
    s1[i0 + 3] = p13; s2[i0 + 3] = p23;
  }
}

// ---------------- kC: rank -> chunk scans -> offsets -> output ---------------
// 64 blocks x 256 threads, 3 cheap grid barriers.
__global__ __launch_bounds__(256) void kC_fused(
    const float* __restrict__ xt, const float* __restrict__ s1,
    const float* __restrict__ s2,
    float* __restrict__ s2s, int* __restrict__ perm,
    float* __restrict__ SP, float* __restrict__ SN,
    float* __restrict__ zP, float* __restrict__ zN,
    float* __restrict__ offP, float* __restrict__ offN,
    float* __restrict__ offZP, float* __restrict__ offZN,
    int* cnt, float* __restrict__ out) {
  __shared__ float keys[NN];     // 16 KiB: unsorted s2, later sorted s2s
  __shared__ int pc[4][64];
  int tid = threadIdx.x, w = tid >> 6, l = tid & 63, b = blockIdx.x;

  // P0: stage unsorted keys
  {
    const float4* s4 = (const float4*)s2;
    float4* kk = (float4*)keys;
#pragma unroll
    for (int u = 0; u < NN / 4 / 256; ++u)
      kk[u * 256 + tid] = s4[u * 256 + tid];
  }
  __syncthreads();

  // P1: rank-by-count; lane owns element e = b*64+l, wave scans 1024-key slice
  {
    int e = b * 64 + l;
    float ke = keys[e];
    const float4* kk4 = (const float4*)keys;
    int c_ = 0;
    for (int q4 = w * 256; q4 < w * 256 + 256; ++q4) {
      float4 kv = kk4[q4];
      int q = q4 * 4;
      c_ += (kv.x < ke || (kv.x == ke && q + 0 < e)) ? 1 : 0;
      c_ += (kv.y < ke || (kv.y == ke && q + 1 < e)) ? 1 : 0;
      c_ += (kv.z < ke || (kv.z == ke && q + 2 < e)) ? 1 : 0;
      c_ += (kv.w < ke || (kv.w == ke && q + 3 < e)) ? 1 : 0;
    }
    pc[w][l] = c_;
    __syncthreads();
    if (w == 0) {
      int rank = pc[0][l] + pc[1][l] + pc[2][l] + pc[3][l];
      s2s[rank] = ke;
      perm[rank] = b * 64 + l;
    }
  }
  gridbar(cnt, 1);

  // P2: reload sorted keys
  {
    const float4* s4 = (const float4*)s2s;
    float4* kk = (float4*)keys;
#pragma unroll
    for (int u = 0; u < NN / 4 / 256; ++u)
      kk[u * 256 + tid] = s4[u * 256 + tid];
  }
  __syncthreads();

  // P3: per-wave chunk scan (chunk cw = b*4+w, CL=16 rows)
  {
    int cw = b * 4 + w, r0 = cw * CL;
    float evP[CL], evN[CL];
    int pmv[CL];
#pragma unroll
    for (int q = 0; q < CL; ++q) {
      float sv = keys[r0 + q];
      evP[q] = expf(sv);
      evN[q] = expf(SLOPE * sv);
    }
#pragma unroll
    for (int q = 0; q < CL; ++q) pmv[q] = perm[r0 + q] * DD;
    float aP = 0.f, aN = 0.f, azP = 0.f, azN = 0.f;
#pragma unroll
    for (int q = 0; q < CL; ++q) {
      float xv = xt[pmv[q] + l];
      aP = fmaf(evP[q], xv, aP);
      aN = fmaf(evN[q], xv, aN);
      azP += evP[q]; azN += evN[q];
      SP[(r0 + q) * DD + l] = aP;
      SN[(r0 + q) * DD + l] = aN;
      if (l == 0) { zP[r0 + q] = azP; zN[r0 + q] = azN; }
    }
  }
  gridbar(cnt, 2);

  // P4: chunk-offset exclusive scans, one wave per prefix column (130 waves)
  {
    int gw = b * 4 + w;
    const float* src = nullptr; float* dst = nullptr; int col = 0, stride = 0;
    if (gw < 64)        { src = SP; dst = offP;  col = gw;      stride = DD; }
    else if (gw < 128)  { src = SN; dst = offN;  col = gw - 64; stride = DD; }
    else if (gw == 128) { src = zP; dst = offZP; col = 0;       stride = 1;  }
    else if (gw == 129) { src = zN; dst = offZN; col = 0;       stride = 1;  }
    if (src) {
      int c0 = 4 * l;
      float v0 = src[((c0 + 0) * CL + CL - 1) * stride + col];
      float v1 = src[((c0 + 1) * CL + CL - 1) * stride + col];
      float v2 = src[((c0 + 2) * CL + CL - 1) * stride + col];
      float v3 = src[((c0 + 3) * CL + CL - 1) * stride + col];
      float p1 = v0, p2 = v0 + v1, p3 = v0 + v1 + v2;
      float T = p3 + v3;
      float incl = T;
#pragma unroll
      for (int off = 1; off < 64; off <<= 1) {
        float t2 = __shfl_up(incl, off, 64);
        if (l >= off) incl += t2;
      }
      float excl = incl - T;
      dst[(c0 + 0) * stride + col] = excl;
      dst[(c0 + 1) * stride + col] = excl + p1;
      dst[(c0 + 2) * stride + col] = excl + p2;
      dst[(c0 + 3) * stride + col] = excl + p3;
      if (l == 63) dst[CH * stride + col] = incl;   // total
    }
  }
  gridbar(cnt, 3);

  // P5: output. Per-lane binary search in LDS keys, then 16 rows per wave.
  {
    float totP = offP[CH * DD + l];
    float totZ = offZP[CH];
    int q0 = l & 15;
    int i = b * 64 + w * 16 + q0;
    float s1v = s1[i];
    float t = -s1v;
    int lo = 0, hi = NN;
#pragma unroll
    for (int it = 0; it < 12; ++it) {
      int mid = (lo + hi) >> 1;
      if (keys[mid] <= t) lo = mid + 1; else hi = mid;
    }
    int kq = lo;   // split: N = [0,kq), P = [kq, NN)
#pragma unroll
    for (int q = 0; q < 16; ++q) {
      int kk_ = __shfl(kq, q, 64);
      float s1q = __shfl(s1v, q, 64);
      float wPq = expf(s1q);
      float wNq = expf(SLOPE * s1q);
      float FPk = 0.f, FNk = 0.f, ZPk = 0.f, ZNk = 0.f;
      if (kk_ > 0) {
        int r = kk_ - 1, c = r >> 4;
        FPk = offP[c * DD + l] + SP[r * DD + l];
        FNk = offN[c * DD + l] + SN[r * DD + l];
        ZPk = offZP[c] + zP[r];
        ZNk = offZN[c] + zN[r];
      }
      float num = wPq * (totP - FPk) + wNq * FNk;
      float den = wPq * (totZ - ZPk) + wNq * ZNk;
      out[(b * 64 + w * 16 + q) * DD + l] = num / den;
    }
  }
}

extern "C" void kernel_launch(void* const* d_in, const int* in_sizes, int n_in,
                              void* d_out, int out_size, void* d_ws, size_t ws_size,
                              hipStream_t stream) {
  const float* x = (const float*)d_in[0];
  const float* W = (const float*)d_in[1];
  const float* a = (const float*)d_in[2];
  float* out = (float*)d_out;

  float* ws = (float*)d_ws;
  float* xt    = ws;                   // NN*DD
  float* s1    = xt + NN * DD;         // NN
  float* s2    = s1 + NN;              // NN
  float* s2s   = s2 + NN;              // NN
  int*   perm  = (int*)(s2s + NN);     // NN
  float* SP    = (float*)(perm + NN);  // NN*DD
  float* SN    = SP + NN * DD;         // NN*DD
  float* zP    = SN + NN * DD;         // NN
  float* zN    = zP + NN;              // NN
  float* offP  = zN + NN;              // (CH+1)*DD
  float* offN  = offP + (CH + 1) * DD; // (CH+1)*DD
  float* offZP = offN + (CH + 1) * DD; // CH+1
  float* offZN = offZP + (CH + 1);     // CH+1
  int*   cnt   = (int*)(offZN + (CH + 1));

  k1_xt<<<NN / 16, 256, 0, stream>>>(x, W, a, xt, s1, s2, cnt);
  kC_fused<<<NBLK, 256, 0, stream>>>(xt, s1, s2, s2s, perm, SP, SN, zP, zN,
                                     offP, offN, offZP, offZN, cnt, out);
}

// Round 5
// 51.974 us; speedup vs baseline: 1.9155x; 1.5906x over previous
//
#include <hip/hip_runtime.h>

#define NN 4096
#define HID 512
#define DD 64
#define SLOPE 0.2f
#define CH 256
#define CL 16   // NN/CH

// ---------------- k1: xt = x@W, s1 = xt@a1, s2 = xt@a2 -----------------------
// W staged in LDS (128 KiB, 1 block/CU). x rows read as broadcast float4.
__global__ __launch_bounds__(256) void k1_xt(
    const float* __restrict__ x, const float* __restrict__ W,
    const float* __restrict__ a,
    float* __restrict__ xt, float* __restrict__ s1, float* __restrict__ s2) {
  __shared__ float Wl[HID * DD];           // 128 KiB
  int tid = threadIdx.x;
  const float4* W4 = (const float4*)W;
  float4* Wl4 = (float4*)Wl;
#pragma unroll
  for (int u = 0; u < (HID * DD / 4) / 256; ++u)   // 32 iters
    Wl4[u * 256 + tid] = W4[u * 256 + tid];
  __syncthreads();
  int w = tid >> 6, l = tid & 63;
  int i0 = blockIdx.x * 16 + w * 4;        // 4 rows per wave
  const float4* xr0 = (const float4*)(x + (size_t)(i0 + 0) * HID);
  const float4* xr1 = (const float4*)(x + (size_t)(i0 + 1) * HID);
  const float4* xr2 = (const float4*)(x + (size_t)(i0 + 2) * HID);
  const float4* xr3 = (const float4*)(x + (size_t)(i0 + 3) * HID);
  float acc0 = 0.f, acc1 = 0.f, acc2 = 0.f, acc3 = 0.f;
#pragma unroll 2
  for (int k4 = 0; k4 < HID / 4; ++k4) {
    float4 xv0 = xr0[k4], xv1 = xr1[k4], xv2 = xr2[k4], xv3 = xr3[k4];
    int k = k4 * 4;
    float w0 = Wl[(k + 0) * DD + l];
    float w1 = Wl[(k + 1) * DD + l];
    float w2 = Wl[(k + 2) * DD + l];
    float w3 = Wl[(k + 3) * DD + l];
    acc0 = fmaf(xv0.x, w0, acc0); acc0 = fmaf(xv0.y, w1, acc0);
    acc0 = fmaf(xv0.z, w2, acc0); acc0 = fmaf(xv0.w, w3, acc0);
    acc1 = fmaf(xv1.x, w0, acc1); acc1 = fmaf(xv1.y, w1, acc1);
    acc1 = fmaf(xv1.z, w2, acc1); acc1 = fmaf(xv1.w, w3, acc1);
    acc2 = fmaf(xv2.x, w0, acc2); acc2 = fmaf(xv2.y, w1, acc2);
    acc2 = fmaf(xv2.z, w2, acc2); acc2 = fmaf(xv2.w, w3, acc2);
    acc3 = fmaf(xv3.x, w0, acc3); acc3 = fmaf(xv3.y, w1, acc3);
    acc3 = fmaf(xv3.z, w2, acc3); acc3 = fmaf(xv3.w, w3, acc3);
  }
  xt[(i0 + 0) * DD + l] = acc0;
  xt[(i0 + 1) * DD + l] = acc1;
  xt[(i0 + 2) * DD + l] = acc2;
  xt[(i0 + 3) * DD + l] = acc3;
  float a1 = a[l], a2 = a[DD + l];
  float p10 = acc0 * a1, p20 = acc0 * a2;
  float p11 = acc1 * a1, p21 = acc1 * a2;
  float p12 = acc2 * a1, p22 = acc2 * a2;
  float p13 = acc3 * a1, p23 = acc3 * a2;
#pragma unroll
  for (int off = 32; off >= 1; off >>= 1) {
    p10 += __shfl_xor(p10, off, 64); p20 += __shfl_xor(p20, off, 64);
    p11 += __shfl_xor(p11, off, 64); p21 += __shfl_xor(p21, off, 64);
    p12 += __shfl_xor(p12, off, 64); p22 += __shfl_xor(p22, off, 64);
    p13 += __shfl_xor(p13, off, 64); p23 += __shfl_xor(p23, off, 64);
  }
  if (l == 0) {
    s1[i0 + 0] = p10; s2[i0 + 0] = p20;
    s1[i0 + 1] = p11; s2[i0 + 1] = p21;
    s1[i0 + 2] = p12; s2[i0 + 2] = p22;
    s1[i0 + 3] = p13; s2[i0 + 3] = p23;
  }
}

// ---------------- k2: rank-by-count -> sorted keys + permutation -------------
// 256 blocks x 256 thr; block ranks 16 elements; each element's count is
// split across 16 replicas scanning 256 keys each.
__global__ __launch_bounds__(256) void k2_rank(
    const float* __restrict__ s2, float* __restrict__ s2s, int* __restrict__ perm) {
  __shared__ float keys[NN];     // 16 KiB
  __shared__ int pc[16][17];
  int tid = threadIdx.x, b = blockIdx.x;
  const float4* s4 = (const float4*)s2;
  float4* kk = (float4*)keys;
#pragma unroll
  for (int u = 0; u < NN / 4 / 256; ++u)   // 4 iters
    kk[u * 256 + tid] = s4[u * 256 + tid];
  __syncthreads();
  int el = tid & 15, rep = tid >> 4;
  int e = b * 16 + el;
  float ke = keys[e];
  const float4* k4p = (const float4*)keys;
  int cnt = 0;
#pragma unroll 4
  for (int q4 = rep * 64; q4 < rep * 64 + 64; ++q4) {
    float4 kv = k4p[q4];
    int q = q4 * 4;
    cnt += (kv.x < ke || (kv.x == ke && q + 0 < e)) ? 1 : 0;
    cnt += (kv.y < ke || (kv.y == ke && q + 1 < e)) ? 1 : 0;
    cnt += (kv.z < ke || (kv.z == ke && q + 2 < e)) ? 1 : 0;
    cnt += (kv.w < ke || (kv.w == ke && q + 3 < e)) ? 1 : 0;
  }
  pc[rep][el] = cnt;
  __syncthreads();
  if (tid < 16) {
    int rank = 0;
#pragma unroll
    for (int r = 0; r < 16; ++r) rank += pc[r][tid];
    s2s[rank] = keys[b * 16 + tid];
    perm[rank] = b * 16 + tid;
  }
}

// ---------------- k3: within-chunk inclusive scans (sorted order) ------------
__global__ __launch_bounds__(256) void k3_scan(
    const float* __restrict__ xt, const float* __restrict__ s2s,
    const int* __restrict__ perm,
    float* __restrict__ SP, float* __restrict__ SN,
    float* __restrict__ zP, float* __restrict__ zN) {
  int tid = threadIdx.x, w = tid >> 6, l = tid & 63;
  int cw = blockIdx.x * 4 + w, r0 = cw * CL;
  float evP[CL], evN[CL];
  int pmv[CL];
#pragma unroll
  for (int q = 0; q < CL; ++q) {
    float sv = s2s[r0 + q];
    evP[q] = expf(sv);
    evN[q] = expf(SLOPE * sv);
  }
#pragma unroll
  for (int q = 0; q < CL; ++q) pmv[q] = perm[r0 + q] * DD;
  float aP = 0.f, aN = 0.f, azP = 0.f, azN = 0.f;
#pragma unroll
  for (int q = 0; q < CL; ++q) {
    float xv = xt[pmv[q] + l];
    aP = fmaf(evP[q], xv, aP);
    aN = fmaf(evN[q], xv, aN);
    azP += evP[q]; azN += evN[q];
    SP[(r0 + q) * DD + l] = aP;
    SN[(r0 + q) * DD + l] = aN;
    if (l == 0) { zP[r0 + q] = azP; zN[r0 + q] = azN; }
  }
}

// ---------------- k4: exclusive scan of chunk totals (130 parallel waves) ----
__global__ __launch_bounds__(256) void k4_off(
    const float* __restrict__ SP, const float* __restrict__ SN,
    const float* __restrict__ zP, const float* __restrict__ zN,
    float* __restrict__ offP, float* __restrict__ offN,
    float* __restrict__ offZP, float* __restrict__ offZN) {
  int tid = threadIdx.x, w = tid >> 6, l = tid & 63;
  int gw = blockIdx.x * 4 + w;
  const float* src = nullptr; float* dst = nullptr; int col = 0, stride = 0;
  if (gw < 64)        { src = SP; dst = offP;  col = gw;      stride = DD; }
  else if (gw < 128)  { src = SN; dst = offN;  col = gw - 64; stride = DD; }
  else if (gw == 128) { src = zP; dst = offZP; col = 0;       stride = 1;  }
  else if (gw == 129) { src = zN; dst = offZN; col = 0;       stride = 1;  }
  if (src) {
    int c0 = 4 * l;
    float v0 = src[((c0 + 0) * CL + CL - 1) * stride + col];
    float v1 = src[((c0 + 1) * CL + CL - 1) * stride + col];
    float v2 = src[((c0 + 2) * CL + CL - 1) * stride + col];
    float v3 = src[((c0 + 3) * CL + CL - 1) * stride + col];
    float p1 = v0, p2 = v0 + v1, p3 = v0 + v1 + v2;
    float T = p3 + v3;
    float incl = T;
#pragma unroll
    for (int off = 1; off < 64; off <<= 1) {
      float t2 = __shfl_up(incl, off, 64);
      if (l >= off) incl += t2;
    }
    float excl = incl - T;
    dst[(c0 + 0) * stride + col] = excl;
    dst[(c0 + 1) * stride + col] = excl + p1;
    dst[(c0 + 2) * stride + col] = excl + p2;
    dst[(c0 + 3) * stride + col] = excl + p3;
    if (l == 63) dst[CH * stride + col] = incl;   // grand total
  }
}

// ---------------- k5: LDS binary search + closed-form output -----------------
__global__ __launch_bounds__(256) void k5_out(
    const float* __restrict__ s1, const float* __restrict__ s2s,
    const float* __restrict__ SP, const float* __restrict__ SN,
    const float* __restrict__ zP, const float* __restrict__ zN,
    const float* __restrict__ offP, const float* __restrict__ offN,
    const float* __restrict__ offZP, const float* __restrict__ offZN,
    float* __restrict__ out) {
  __shared__ float keys[NN];     // sorted keys, 16 KiB
  int tid = threadIdx.x, w = tid >> 6, l = tid & 63, b = blockIdx.x;
  const float4* s4 = (const float4*)s2s;
  float4* kk = (float4*)keys;
#pragma unroll
  for (int u = 0; u < NN / 4 / 256; ++u)
    kk[u * 256 + tid] = s4[u * 256 + tid];
  __syncthreads();
  float totP = offP[CH * DD + l];
  float totZ = offZP[CH];
  int q0 = l & 15;
  int i = b * 64 + w * 16 + q0;
  float s1v = s1[i];
  float t = -s1v;
  int lo = 0, hi = NN;
#pragma unroll
  for (int it = 0; it < 12; ++it) {
    int mid = (lo + hi) >> 1;
    if (keys[mid] <= t) lo = mid + 1; else hi = mid;
  }
  int kq = lo;   // split: N = [0,kq), P = [kq, NN)
#pragma unroll
  for (int q = 0; q < 16; ++q) {
    int kk_ = __shfl(kq, q, 64);
    float s1q = __shfl(s1v, q, 64);
    float wPq = expf(s1q);
    float wNq = expf(SLOPE * s1q);
    float FPk = 0.f, FNk = 0.f, ZPk = 0.f, ZNk = 0.f;
    if (kk_ > 0) {
      int r = kk_ - 1, c = r >> 4;
      FPk = offP[c * DD + l] + SP[r * DD + l];
      FNk = offN[c * DD + l] + SN[r * DD + l];
      ZPk = offZP[c] + zP[r];
      ZNk = offZN[c] + zN[r];
    }
    float num = wPq * (totP - FPk) + wNq * FNk;
    float den = wPq * (totZ - ZPk) + wNq * ZNk;
    out[(b * 64 + w * 16 + q) * DD + l] = num / den;
  }
}

extern "C" void kernel_launch(void* const* d_in, const int* in_sizes, int n_in,
                              void* d_out, int out_size, void* d_ws, size_t ws_size,
                              hipStream_t stream) {
  const float* x = (const float*)d_in[0];
  const float* W = (const float*)d_in[1];
  const float* a = (const float*)d_in[2];
  float* out = (float*)d_out;

  float* ws = (float*)d_ws;
  float* xt    = ws;                   // NN*DD
  float* s1    = xt + NN * DD;         // NN
  float* s2    = s1 + NN;              // NN
  float* s2s   = s2 + NN;              // NN
  int*   perm  = (int*)(s2s + NN);     // NN
  float* SP    = (float*)(perm + NN);  // NN*DD
  float* SN    = SP + NN * DD;         // NN*DD
  float* zP    = SN + NN * DD;         // NN
  float* zN    = zP + NN;              // NN
  float* offP  = zN + NN;              // (CH+1)*DD
  float* offN  = offP + (CH + 1) * DD; // (CH+1)*DD
  float* offZP = offN + (CH + 1) * DD; // CH+1
  float* offZN = offZP + (CH + 1);     // CH+1

  k1_xt<<<NN / 16, 256, 0, stream>>>(x, W, a, xt, s1, s2);
  k2_rank<<<NN / 16, 256, 0, stream>>>(s2, s2s, perm);
  k3_scan<<<CH / 4, 256, 0, stream>>>(xt, s2s, perm, SP, SN, zP, zN);
  k4_off<<<33, 256, 0, stream>>>(SP, SN, zP, zN, offP, offN, offZP, offZN);
  k5_out<<<NN / 64, 256, 0, stream>>>(s1, s2s, SP, SN, zP, zN,
                                      offP, offN, offZP, offZN, out);
}

// Round 6
// 46.744 us; speedup vs baseline: 2.1298x; 1.1119x over previous
//
#include <hip/hip_runtime.h>

#define NN 4096
#define HID 512
#define DD 64
#define SLOPE 0.2f
#define CH 1024
#define CL 4    // NN/CH

// ---------------- k1: xt = x@W, s1 = xt@a1, s2 = xt@a2 -----------------------
// W staged in LDS in two 64 KiB halves -> 2 blocks/CU (2 waves/SIMD).
__global__ __launch_bounds__(256) void k1_xt(
    const float* __restrict__ x, const float* __restrict__ W,
    const float* __restrict__ a,
    float* __restrict__ xt, float* __restrict__ s1, float* __restrict__ s2) {
  __shared__ float Wl[256 * DD];           // 64 KiB
  int tid = threadIdx.x;
  int w = tid >> 6, l = tid & 63;
  int i0 = blockIdx.x * 16 + w * 4;        // 4 rows per wave
  const float4* xr0 = (const float4*)(x + (size_t)(i0 + 0) * HID);
  const float4* xr1 = (const float4*)(x + (size_t)(i0 + 1) * HID);
  const float4* xr2 = (const float4*)(x + (size_t)(i0 + 2) * HID);
  const float4* xr3 = (const float4*)(x + (size_t)(i0 + 3) * HID);
  float acc0 = 0.f, acc1 = 0.f, acc2 = 0.f, acc3 = 0.f;
#pragma unroll
  for (int half = 0; half < 2; ++half) {
    __syncthreads();                        // previous-pass readers done
    const float4* W4 = (const float4*)(W + half * 256 * DD);
    float4* Wl4 = (float4*)Wl;
#pragma unroll
    for (int u = 0; u < (256 * DD / 4) / 256; ++u)   // 16 iters
      Wl4[u * 256 + tid] = W4[u * 256 + tid];
    __syncthreads();
#pragma unroll 2
    for (int k4 = 0; k4 < 64; ++k4) {
      int kg = half * 64 + k4;              // global float4 index in row
      float4 xv0 = xr0[kg], xv1 = xr1[kg], xv2 = xr2[kg], xv3 = xr3[kg];
      int k = k4 * 4;
      float w0 = Wl[(k + 0) * DD + l];
      float w1 = Wl[(k + 1) * DD + l];
      float w2 = Wl[(k + 2) * DD + l];
      float w3 = Wl[(k + 3) * DD + l];
      acc0 = fmaf(xv0.x, w0, acc0); acc0 = fmaf(xv0.y, w1, acc0);
      acc0 = fmaf(xv0.z, w2, acc0); acc0 = fmaf(xv0.w, w3, acc0);
      acc1 = fmaf(xv1.x, w0, acc1); acc1 = fmaf(xv1.y, w1, acc1);
      acc1 = fmaf(xv1.z, w2, acc1); acc1 = fmaf(xv1.w, w3, acc1);
      acc2 = fmaf(xv2.x, w0, acc2); acc2 = fmaf(xv2.y, w1, acc2);
      acc2 = fmaf(xv2.z, w2, acc2); acc2 = fmaf(xv2.w, w3, acc2);
      acc3 = fmaf(xv3.x, w0, acc3); acc3 = fmaf(xv3.y, w1, acc3);
      acc3 = fmaf(xv3.z, w2, acc3); acc3 = fmaf(xv3.w, w3, acc3);
    }
  }
  xt[(i0 + 0) * DD + l] = acc0;
  xt[(i0 + 1) * DD + l] = acc1;
  xt[(i0 + 2) * DD + l] = acc2;
  xt[(i0 + 3) * DD + l] = acc3;
  float a1 = a[l], a2 = a[DD + l];
  float p10 = acc0 * a1, p20 = acc0 * a2;
  float p11 = acc1 * a1, p21 = acc1 * a2;
  float p12 = acc2 * a1, p22 = acc2 * a2;
  float p13 = acc3 * a1, p23 = acc3 * a2;
#pragma unroll
  for (int off = 32; off >= 1; off >>= 1) {
    p10 += __shfl_xor(p10, off, 64); p20 += __shfl_xor(p20, off, 64);
    p11 += __shfl_xor(p11, off, 64); p21 += __shfl_xor(p21, off, 64);
    p12 += __shfl_xor(p12, off, 64); p22 += __shfl_xor(p22, off, 64);
    p13 += __shfl_xor(p13, off, 64); p23 += __shfl_xor(p23, off, 64);
  }
  if (l == 0) {
    s1[i0 + 0] = p10; s2[i0 + 0] = p20;
    s1[i0 + 1] = p11; s2[i0 + 1] = p21;
    s1[i0 + 2] = p12; s2[i0 + 2] = p22;
    s1[i0 + 3] = p13; s2[i0 + 3] = p23;
  }
}

// ---------------- k2: rank-by-count -> sorted keys + permutation -------------
__global__ __launch_bounds__(256) void k2_rank(
    const float* __restrict__ s2, float* __restrict__ s2s, int* __restrict__ perm) {
  __shared__ float keys[NN];     // 16 KiB
  __shared__ int pc[16][17];
  int tid = threadIdx.x, b = blockIdx.x;
  const float4* s4 = (const float4*)s2;
  float4* kk = (float4*)keys;
#pragma unroll
  for (int u = 0; u < NN / 4 / 256; ++u)   // 4 iters
    kk[u * 256 + tid] = s4[u * 256 + tid];
  __syncthreads();
  int el = tid & 15, rep = tid >> 4;
  int e = b * 16 + el;
  float ke = keys[e];
  const float4* k4p = (const float4*)keys;
  int cnt = 0;
#pragma unroll 4
  for (int q4 = rep * 64; q4 < rep * 64 + 64; ++q4) {
    float4 kv = k4p[q4];
    int q = q4 * 4;
    cnt += (kv.x < ke || (kv.x == ke && q + 0 < e)) ? 1 : 0;
    cnt += (kv.y < ke || (kv.y == ke && q + 1 < e)) ? 1 : 0;
    cnt += (kv.z < ke || (kv.z == ke && q + 2 < e)) ? 1 : 0;
    cnt += (kv.w < ke || (kv.w == ke && q + 3 < e)) ? 1 : 0;
  }
  pc[rep][el] = cnt;
  __syncthreads();
  if (tid < 16) {
    int rank = 0;
#pragma unroll
    for (int r = 0; r < 16; ++r) rank += pc[r][tid];
    s2s[rank] = keys[b * 16 + tid];
    perm[rank] = b * 16 + tid;
  }
}

// ---------------- k3: within-chunk inclusive scans (CL=4, 1024 waves) --------
__global__ __launch_bounds__(256) void k3_scan(
    const float* __restrict__ xt, const float* __restrict__ s2s,
    const int* __restrict__ perm,
    float* __restrict__ SP, float* __restrict__ SN,
    float* __restrict__ zP, float* __restrict__ zN) {
  int tid = threadIdx.x, w = tid >> 6, l = tid & 63;
  int cw = blockIdx.x * 4 + w, r0 = cw * CL;
  float evP[CL], evN[CL], xv[CL];
  int pmv[CL];
#pragma unroll
  for (int q = 0; q < CL; ++q) {
    float sv = s2s[r0 + q];
    evP[q] = expf(sv);
    evN[q] = expf(SLOPE * sv);
  }
#pragma unroll
  for (int q = 0; q < CL; ++q) pmv[q] = perm[r0 + q] * DD;
#pragma unroll
  for (int q = 0; q < CL; ++q) xv[q] = xt[pmv[q] + l];   // 4 parallel gathers
  float aP = 0.f, aN = 0.f, azP = 0.f, azN = 0.f;
#pragma unroll
  for (int q = 0; q < CL; ++q) {
    aP = fmaf(evP[q], xv[q], aP);
    aN = fmaf(evN[q], xv[q], aN);
    azP += evP[q]; azN += evN[q];
    SP[(r0 + q) * DD + l] = aP;
    SN[(r0 + q) * DD + l] = aN;
    if (l == 0) { zP[r0 + q] = azP; zN[r0 + q] = azN; }
  }
}

// ---------------- k4: exclusive scan of chunk totals (130 parallel waves) ----
__global__ __launch_bounds__(256) void k4_off(
    const float* __restrict__ SP, const float* __restrict__ SN,
    const float* __restrict__ zP, const float* __restrict__ zN,
    float* __restrict__ offP, float* __restrict__ offN,
    float* __restrict__ offZP, float* __restrict__ offZN) {
  int tid = threadIdx.x, w = tid >> 6, l = tid & 63;
  int gw = blockIdx.x * 4 + w;
  const float* src = nullptr; float* dst = nullptr; int col = 0, stride = 0;
  if (gw < 64)        { src = SP; dst = offP;  col = gw;      stride = DD; }
  else if (gw < 128)  { src = SN; dst = offN;  col = gw - 64; stride = DD; }
  else if (gw == 128) { src = zP; dst = offZP; col = 0;       stride = 1;  }
  else if (gw == 129) { src = zN; dst = offZN; col = 0;       stride = 1;  }
  if (src) {
    int c0 = 16 * l;                        // 16 chunks per lane
    float v[16], p[16];
#pragma unroll
    for (int j = 0; j < 16; ++j)
      v[j] = src[((c0 + j) * CL + CL - 1) * stride + col];
    float run = 0.f;
#pragma unroll
    for (int j = 0; j < 16; ++j) { p[j] = run; run += v[j]; }
    float T = run;
    float incl = T;
#pragma unroll
    for (int off = 1; off < 64; off <<= 1) {
      float t2 = __shfl_up(incl, off, 64);
      if (l >= off) incl += t2;
    }
    float excl = incl - T;
#pragma unroll
    for (int j = 0; j < 16; ++j)
      dst[(c0 + j) * stride + col] = excl + p[j];
    if (l == 63) dst[CH * stride + col] = incl;   // grand total
  }
}

// ---------------- k5: LDS binary search + closed-form output (4 rows/wave) ---
__global__ __launch_bounds__(256) void k5_out(
    const float* __restrict__ s1, const float* __restrict__ s2s,
    const float* __restrict__ SP, const float* __restrict__ SN,
    const float* __restrict__ zP, const float* __restrict__ zN,
    const float* __restrict__ offP, const float* __restrict__ offN,
    const float* __restrict__ offZP, const float* __restrict__ offZN,
    float* __restrict__ out) {
  __shared__ float keys[NN];     // sorted keys, 16 KiB
  int tid = threadIdx.x, w = tid >> 6, l = tid & 63, b = blockIdx.x;
  const float4* s4 = (const float4*)s2s;
  float4* kk = (float4*)keys;
#pragma unroll
  for (int u = 0; u < NN / 4 / 256; ++u)
    kk[u * 256 + tid] = s4[u * 256 + tid];
  __syncthreads();
  float totP = offP[CH * DD + l];
  float totZ = offZP[CH];
  int q0 = l & 3;
  int i = b * 16 + w * 4 + q0;
  float s1v = s1[i];
  float t = -s1v;
  int lo = 0, hi = NN;
#pragma unroll
  for (int it = 0; it < 12; ++it) {
    int mid = (lo + hi) >> 1;
    if (keys[mid] <= t) lo = mid + 1; else hi = mid;
  }
  int kq = lo;   // split: N = [0,kq), P = [kq, NN)
#pragma unroll
  for (int q = 0; q < 4; ++q) {
    int kk_ = __shfl(kq, q, 64);
    float s1q = __shfl(s1v, q, 64);
    float wPq = expf(s1q);
    float wNq = expf(SLOPE * s1q);
    float FPk = 0.f, FNk = 0.f, ZPk = 0.f, ZNk = 0.f;
    if (kk_ > 0) {
      int r = kk_ - 1, c = r >> 2;
      FPk = offP[c * DD + l] + SP[r * DD + l];
      FNk = offN[c * DD + l] + SN[r * DD + l];
      ZPk = offZP[c] + zP[r];
      ZNk = offZN[c] + zN[r];
    }
    float num = wPq * (totP - FPk) + wNq * FNk;
    float den = wPq * (totZ - ZPk) + wNq * ZNk;
    out[(b * 16 + w * 4 + q) * DD + l] = num / den;
  }
}

extern "C" void kernel_launch(void* const* d_in, const int* in_sizes, int n_in,
                              void* d_out, int out_size, void* d_ws, size_t ws_size,
                              hipStream_t stream) {
  const float* x = (const float*)d_in[0];
  const float* W = (const float*)d_in[1];
  const float* a = (const float*)d_in[2];
  float* out = (float*)d_out;

  float* ws = (float*)d_ws;
  float* xt    = ws;                   // NN*DD
  float* s1    = xt + NN * DD;         // NN
  float* s2    = s1 + NN;              // NN
  float* s2s   = s2 + NN;              // NN
  int*   perm  = (int*)(s2s + NN);     // NN
  float* SP    = (float*)(perm + NN);  // NN*DD
  float* SN    = SP + NN * DD;         // NN*DD
  float* zP    = SN + NN * DD;         // NN
  float* zN    = zP + NN;              // NN
  float* offP  = zN + NN;              // (CH+1)*DD
  float* offN  = offP + (CH + 1) * DD; // (CH+1)*DD
  float* offZP = offN + (CH + 1) * DD; // CH+1
  float* offZN = offZP + (CH + 1);     // CH+1

  k1_xt<<<NN / 16, 256, 0, stream>>>(x, W, a, xt, s1, s2);
  k2_rank<<<NN / 16, 256, 0, stream>>>(s2, s2s, perm);
  k3_scan<<<CH / 4, 256, 0, stream>>>(xt, s2s, perm, SP, SN, zP, zN);
  k4_off<<<33, 256, 0, stream>>>(SP, SN, zP, zN, offP, offN, offZP, offZN);
  k5_out<<<NN / 16, 256, 0, stream>>>(s1, s2s, SP, SN, zP, zN,
                                      offP, offN, offZP, offZN, out);
}

// Round 7
// 46.567 us; speedup vs baseline: 2.1379x; 1.0038x over previous
//
#include <hip/hip_runtime.h>

#define NN 4096
#define HID 512
#define DD 64
#define SLOPE 0.2f
// hierarchy: 8 rows/chunk, 8 chunks/seg (64 rows), 8 segs/block (512 rows), 8 blocks
#define NCHUNK 512
#define NSEG 64
#define NBLK8 8

// ---------------- kA: xt = x@W, s1 = xt@a1, s2 = xt@a2 -----------------------
__global__ __launch_bounds__(256) void kA_xt(
    const float* __restrict__ x, const float* __restrict__ W,
    const float* __restrict__ a,
    float* __restrict__ xt, float* __restrict__ s1, float* __restrict__ s2) {
  __shared__ float Wl[256 * DD];           // 64 KiB half
  int tid = threadIdx.x;
  int w = tid >> 6, l = tid & 63;
  int i0 = blockIdx.x * 16 + w * 4;        // 4 rows per wave
  const float4* xr0 = (const float4*)(x + (size_t)(i0 + 0) * HID);
  const float4* xr1 = (const float4*)(x + (size_t)(i0 + 1) * HID);
  const float4* xr2 = (const float4*)(x + (size_t)(i0 + 2) * HID);
  const float4* xr3 = (const float4*)(x + (size_t)(i0 + 3) * HID);
  float acc0 = 0.f, acc1 = 0.f, acc2 = 0.f, acc3 = 0.f;
#pragma unroll
  for (int half = 0; half < 2; ++half) {
    __syncthreads();
    const float4* W4 = (const float4*)(W + half * 256 * DD);
    float4* Wl4 = (float4*)Wl;
#pragma unroll
    for (int u = 0; u < (256 * DD / 4) / 256; ++u)
      Wl4[u * 256 + tid] = W4[u * 256 + tid];
    __syncthreads();
#pragma unroll 2
    for (int k4 = 0; k4 < 64; ++k4) {
      int kg = half * 64 + k4;
      float4 xv0 = xr0[kg], xv1 = xr1[kg], xv2 = xr2[kg], xv3 = xr3[kg];
      int k = k4 * 4;
      float w0 = Wl[(k + 0) * DD + l];
      float w1 = Wl[(k + 1) * DD + l];
      float w2 = Wl[(k + 2) * DD + l];
      float w3 = Wl[(k + 3) * DD + l];
      acc0 = fmaf(xv0.x, w0, acc0); acc0 = fmaf(xv0.y, w1, acc0);
      acc0 = fmaf(xv0.z, w2, acc0); acc0 = fmaf(xv0.w, w3, acc0);
      acc1 = fmaf(xv1.x, w0, acc1); acc1 = fmaf(xv1.y, w1, acc1);
      acc1 = fmaf(xv1.z, w2, acc1); acc1 = fmaf(xv1.w, w3, acc1);
      acc2 = fmaf(xv2.x, w0, acc2); acc2 = fmaf(xv2.y, w1, acc2);
      acc2 = fmaf(xv2.z, w2, acc2); acc2 = fmaf(xv2.w, w3, acc2);
      acc3 = fmaf(xv3.x, w0, acc3); acc3 = fmaf(xv3.y, w1, acc3);
      acc3 = fmaf(xv3.z, w2, acc3); acc3 = fmaf(xv3.w, w3, acc3);
    }
  }
  xt[(i0 + 0) * DD + l] = acc0;
  xt[(i0 + 1) * DD + l] = acc1;
  xt[(i0 + 2) * DD + l] = acc2;
  xt[(i0 + 3) * DD + l] = acc3;
  float a1 = a[l], a2 = a[DD + l];
  float p10 = acc0 * a1, p20 = acc0 * a2;
  float p11 = acc1 * a1, p21 = acc1 * a2;
  float p12 = acc2 * a1, p22 = acc2 * a2;
  float p13 = acc3 * a1, p23 = acc3 * a2;
#pragma unroll
  for (int off = 32; off >= 1; off >>= 1) {
    p10 += __shfl_xor(p10, off, 64); p20 += __shfl_xor(p20, off, 64);
    p11 += __shfl_xor(p11, off, 64); p21 += __shfl_xor(p21, off, 64);
    p12 += __shfl_xor(p12, off, 64); p22 += __shfl_xor(p22, off, 64);
    p13 += __shfl_xor(p13, off, 64); p23 += __shfl_xor(p23, off, 64);
  }
  if (l == 0) {
    s1[i0 + 0] = p10; s2[i0 + 0] = p20;
    s1[i0 + 1] = p11; s2[i0 + 1] = p21;
    s1[i0 + 2] = p12; s2[i0 + 2] = p22;
    s1[i0 + 3] = p13; s2[i0 + 3] = p23;
  }
}

// ---------------- kB: rank-by-count + split index --------------------------
// 256 blocks x 256 thr. Block b handles elements/rows b*16..b*16+15:
//  rank of s2[e] among all s2 (stable) -> s2s, perm
//  kidx[i] = #{j : s2[j] <= -s1[i]}  (split point for row i)
__global__ __launch_bounds__(256) void kB_rank(
    const float* __restrict__ s2, const float* __restrict__ s1,
    float* __restrict__ s2s, int* __restrict__ perm, int* __restrict__ kidx) {
  __shared__ float keys[NN];     // 16 KiB
  __shared__ int pc[16][17];
  __shared__ int pk[16][17];
  int tid = threadIdx.x, b = blockIdx.x;
  const float4* s4 = (const float4*)s2;
  float4* kk = (float4*)keys;
#pragma unroll
  for (int u = 0; u < NN / 4 / 256; ++u)
    kk[u * 256 + tid] = s4[u * 256 + tid];
  __syncthreads();
  int el = tid & 15, rep = tid >> 4;
  int e = b * 16 + el;
  float ke = keys[e];
  float te = -s1[e];
  const float4* k4p = (const float4*)keys;
  int cnt = 0, ck = 0;
#pragma unroll 4
  for (int q4 = rep * 64; q4 < rep * 64 + 64; ++q4) {
    float4 kv = k4p[q4];
    int q = q4 * 4;
    cnt += (kv.x < ke || (kv.x == ke && q + 0 < e)) ? 1 : 0;
    cnt += (kv.y < ke || (kv.y == ke && q + 1 < e)) ? 1 : 0;
    cnt += (kv.z < ke || (kv.z == ke && q + 2 < e)) ? 1 : 0;
    cnt += (kv.w < ke || (kv.w == ke && q + 3 < e)) ? 1 : 0;
    ck += (kv.x <= te) ? 1 : 0;
    ck += (kv.y <= te) ? 1 : 0;
    ck += (kv.z <= te) ? 1 : 0;
    ck += (kv.w <= te) ? 1 : 0;
  }
  pc[rep][el] = cnt;
  pk[rep][el] = ck;
  __syncthreads();
  if (tid < 16) {
    int rank = 0, kx = 0;
#pragma unroll
    for (int r = 0; r < 16; ++r) { rank += pc[r][tid]; kx += pk[r][tid]; }
    s2s[rank] = keys[b * 16 + tid];
    perm[rank] = b * 16 + tid;
    kidx[b * 16 + tid] = kx;
  }
}

// ---------------- kC: hierarchical sums (chunk/seg/block) + exp pairs --------
// 8 blocks x 512 thr (8 waves). Block B owns sorted rows [B*512, B*512+512).
// Wave w owns seg s = B*8+w (64 rows = 8 chunks of 8).
__global__ __launch_bounds__(512) void kC_sums(
    const float* __restrict__ xt, const float* __restrict__ s2s,
    const int* __restrict__ perm,
    float2* __restrict__ EPN,
    float* __restrict__ CSP, float* __restrict__ CSN, float2* __restrict__ CZ,
    float* __restrict__ SGP, float* __restrict__ SGN, float2* __restrict__ SZ,
    float* __restrict__ BSP, float* __restrict__ BSN, float2* __restrict__ BZ) {
  __shared__ float2 evL[512];        // per-row (eP,eN) for the block's rows
  __shared__ float segPL[8][64], segNL[8][64];
  __shared__ float2 szL[8];
  int tid = threadIdx.x, w = tid >> 6, l = tid & 63, B = blockIdx.x;
  int segBase = B * 512 + w * 64;    // first sorted row of this wave's seg
  int seg = B * 8 + w;

  // per-row exp pair (lane-parallel: one row per lane)
  int row = segBase + l;
  float key = s2s[row];
  float eP = __expf(key) * 0.f + expf(key);    // keep precise expf
  float eN = expf(SLOPE * key);
  EPN[row] = make_float2(eP, eN);
  evL[w * 64 + l] = make_float2(eP, eN);
  int pmv = perm[row];               // this lane's row's source index

  // Z sums via shfl-xor tree: chunk level (width 8), then seg level
  float zp = eP, zn = eN;
#pragma unroll
  for (int off = 1; off <= 4; off <<= 1) {
    zp += __shfl_xor(zp, off, 64);
    zn += __shfl_xor(zn, off, 64);
  }
  if ((l & 7) == 0) CZ[seg * 8 + (l >> 3)] = make_float2(zp, zn);
#pragma unroll
  for (int off = 8; off <= 32; off <<= 1) {
    zp += __shfl_xor(zp, off, 64);
    zn += __shfl_xor(zn, off, 64);
  }
  if (l == 0) { SZ[seg] = make_float2(zp, zn); szL[w] = make_float2(zp, zn); }

  // chunk sums (vector, lane = dim d); seg accumulation
  float segP = 0.f, segN = 0.f;
#pragma unroll
  for (int c = 0; c < 8; ++c) {
    float cP = 0.f, cN = 0.f;
#pragma unroll
    for (int rr = 0; rr < 8; ++rr) {
      int pm = __shfl(pmv, c * 8 + rr, 64);
      float xv = xt[pm * DD + l];
      float2 ev = evL[w * 64 + c * 8 + rr];
      cP = fmaf(ev.x, xv, cP);
      cN = fmaf(ev.y, xv, cN);
    }
    CSP[(seg * 8 + c) * DD + l] = cP;
    CSN[(seg * 8 + c) * DD + l] = cN;
    segP += cP; segN += cN;
  }
  SGP[seg * DD + l] = segP;
  SGN[seg * DD + l] = segN;
  segPL[w][l] = segP; segNL[w][l] = segN;
  __syncthreads();

  // block totals (wave 0)
  if (w == 0) {
    float bP = 0.f, bN = 0.f;
#pragma unroll
    for (int s = 0; s < 8; ++s) { bP += segPL[s][l]; bN += segNL[s][l]; }
    BSP[B * DD + l] = bP;
    BSN[B * DD + l] = bN;
    if (l == 0) {
      float2 bz = make_float2(0.f, 0.f);
#pragma unroll
      for (int s = 0; s < 8; ++s) { bz.x += szL[s].x; bz.y += szL[s].y; }
      BZ[B] = bz;
    }
  }
}

// ---------------- kD: per-row output from hierarchical partials --------------
// 256 blocks x 256 thr; 4 rows per wave (lane = dim d).
__global__ __launch_bounds__(256) void kD_out(
    const float* __restrict__ xt, const float* __restrict__ s1,
    const int* __restrict__ perm, const int* __restrict__ kidx,
    const float2* __restrict__ EPN,
    const float* __restrict__ CSP, const float* __restrict__ CSN,
    const float2* __restrict__ CZ,
    const float* __restrict__ SGP, const float* __restrict__ SGN,
    const float2* __restrict__ SZ,
    const float* __restrict__ BSP, const float* __restrict__ BSN,
    const float2* __restrict__ BZ,
    float* __restrict__ out) {
  int tid = threadIdx.x, w = tid >> 6, l = tid & 63, b = blockIdx.x;
  int i = b * 16 + w * 4 + (l & 3);
  float s1v = s1[i];
  int kq = kidx[i];

  // grand totals (P side only needed)
  float totP = 0.f, totZ = 0.f;
#pragma unroll
  for (int j = 0; j < 8; ++j) {
    totP += BSP[j * DD + l];
    totZ += BZ[j].x;
  }

#pragma unroll
  for (int q = 0; q < 4; ++q) {
    int kk_ = __shfl(kq, q, 64);
    float s1q = __shfl(s1v, q, 64);
    float wP = expf(s1q);
    float wN = expf(SLOPE * s1q);
    float FPk = 0.f, FNk = 0.f, ZPk = 0.f, ZNk = 0.f;
    if (kk_ > 0) {
      int r = kk_ - 1;
      int br = r >> 9, sr = (r >> 6) & 7, cr = (r >> 3) & 7;
      int segg = r >> 6, base = r & ~7, rlim = r & 7;
      // full blocks below
#pragma unroll
      for (int j = 0; j < 7; ++j) {
        float vP = BSP[j * DD + l], vN = BSN[j * DD + l];
        float2 z = BZ[j];
        bool p = j < br;
        FPk += p ? vP : 0.f; FNk += p ? vN : 0.f;
        ZPk += p ? z.x : 0.f; ZNk += p ? z.y : 0.f;
      }
      // full segs below within block br
#pragma unroll
      for (int j = 0; j < 7; ++j) {
        int idx = (br << 3) + j;
        float vP = SGP[idx * DD + l], vN = SGN[idx * DD + l];
        float2 z = SZ[idx];
        bool p = j < sr;
        FPk += p ? vP : 0.f; FNk += p ? vN : 0.f;
        ZPk += p ? z.x : 0.f; ZNk += p ? z.y : 0.f;
      }
      // full chunks below within seg
#pragma unroll
      for (int j = 0; j < 7; ++j) {
        int idx = (segg << 3) + j;
        float vP = CSP[idx * DD + l], vN = CSN[idx * DD + l];
        float2 z = CZ[idx];
        bool p = j < cr;
        FPk += p ? vP : 0.f; FNk += p ? vN : 0.f;
        ZPk += p ? z.x : 0.f; ZNk += p ? z.y : 0.f;
      }
      // rows within chunk
#pragma unroll
      for (int j = 0; j < 8; ++j) {
        int rw = base + j;
        float2 ev = EPN[rw];
        int pm = perm[rw];
        float xv = xt[pm * DD + l];
        bool p = j <= rlim;
        FPk = fmaf(p ? ev.x : 0.f, xv, FPk);
        FNk = fmaf(p ? ev.y : 0.f, xv, FNk);
        ZPk += p ? ev.x : 0.f; ZNk += p ? ev.y : 0.f;
      }
    }
    float num = wP * (totP - FPk) + wN * FNk;
    float den = wP * (totZ - ZPk) + wN * ZNk;
    out[(b * 16 + w * 4 + q) * DD + l] = num / den;
  }
}

extern "C" void kernel_launch(void* const* d_in, const int* in_sizes, int n_in,
                              void* d_out, int out_size, void* d_ws, size_t ws_size,
                              hipStream_t stream) {
  const float* x = (const float*)d_in[0];
  const float* W = (const float*)d_in[1];
  const float* a = (const float*)d_in[2];
  float* out = (float*)d_out;

  float* ws = (float*)d_ws;
  float*  xt   = ws;                     // 262144
  float*  s1   = xt + NN * DD;           // 4096
  float*  s2   = s1 + NN;                // 4096
  float*  s2s  = s2 + NN;                // 4096
  int*    perm = (int*)(s2s + NN);       // 4096
  int*    kidx = perm + NN;              // 4096
  float2* EPN  = (float2*)(kidx + NN);   // 4096 float2
  float*  CSP  = (float*)(EPN + NN);     // 512*64
  float*  CSN  = CSP + NCHUNK * DD;      // 512*64
  float2* CZ   = (float2*)(CSN + NCHUNK * DD);   // 512 float2
  float*  SGP  = (float*)(CZ + NCHUNK);  // 64*64
  float*  SGN  = SGP + NSEG * DD;        // 64*64
  float2* SZ   = (float2*)(SGN + NSEG * DD);     // 64 float2
  float*  BSP  = (float*)(SZ + NSEG);    // 8*64
  float*  BSN  = BSP + NBLK8 * DD;       // 8*64
  float2* BZ   = (float2*)(BSN + NBLK8 * DD);    // 8 float2

  kA_xt<<<NN / 16, 256, 0, stream>>>(x, W, a, xt, s1, s2);
  kB_rank<<<NN / 16, 256, 0, stream>>>(s2, s1, s2s, perm, kidx);
  kC_sums<<<NBLK8, 512, 0, stream>>>(xt, s2s, perm, EPN, CSP, CSN, CZ,
                                     SGP, SGN, SZ, BSP, BSN, BZ);
  kD_out<<<NN / 16, 256, 0, stream>>>(xt, s1, perm, kidx, EPN, CSP, CSN, CZ,
                                      SGP, SGN, SZ, BSP, BSN, BZ, out);
}

// Round 8
// 41.605 us; speedup vs baseline: 2.3929x; 1.1193x over previous
//
#include <hip/hip_runtime.h>

#define NN 4096
#define HID 512
#define DD 64
#define SLOPE 0.2f
// hierarchy: 8 rows/chunk, 8 chunks/seg (64 rows), 8 segs/block (512 rows), 8 blocks
#define NCHUNK 512
#define NSEG 64
#define NBLK8 8

// ---------------- kA: xt = x@W, s1 = xt@a1, s2 = xt@a2 -----------------------
// v2: 8 rows/block (grid 512, 2 blocks/CU), x slab coalesced-staged in LDS,
// W in 4 k-chunks of 32 KiB. 2 rows/wave.
__global__ __launch_bounds__(256) void kA_xt(
    const float* __restrict__ x, const float* __restrict__ W,
    const float* __restrict__ a,
    float* __restrict__ xt, float* __restrict__ s1, float* __restrict__ s2) {
  __shared__ float xs[8 * HID];            // 16 KiB: block's 8 rows of x
  __shared__ float Wc[128 * DD];           // 32 KiB: one k-chunk of W
  int tid = threadIdx.x;
  int w = tid >> 6, l = tid & 63;
  int i0 = blockIdx.x * 8;                 // first row of block

  // stage x slab: 1024 float4, coalesced, all independent
  {
    const float4* xg = (const float4*)(x + (size_t)i0 * HID);
    float4* xs4 = (float4*)xs;
#pragma unroll
    for (int j = 0; j < 4; ++j)
      xs4[j * 256 + tid] = xg[j * 256 + tid];
  }

  int r0 = w * 2, r1 = w * 2 + 1;          // this wave's rows (local)
  float acc0 = 0.f, acc1 = 0.f;
  const float4* xs4 = (const float4*)xs;

#pragma unroll
  for (int c = 0; c < 4; ++c) {
    __syncthreads();                       // readers of previous chunk done
    // stage W chunk c: rows [c*128, c*128+128) of W -> 2048 float4
    {
      const float4* Wg = (const float4*)(W + (size_t)c * 128 * DD);
      float4* Wc4 = (float4*)Wc;
#pragma unroll
      for (int j = 0; j < 8; ++j)
        Wc4[j * 256 + tid] = Wg[j * 256 + tid];
    }
    __syncthreads();
#pragma unroll 4
    for (int k4 = 0; k4 < 32; ++k4) {      // float4 groups within chunk
      float4 xv0 = xs4[r0 * (HID / 4) + c * 32 + k4];  // broadcast b128
      float4 xv1 = xs4[r1 * (HID / 4) + c * 32 + k4];
      int k = k4 * 4;
      float w0 = Wc[(k + 0) * DD + l];
      float w1 = Wc[(k + 1) * DD + l];
      float w2 = Wc[(k + 2) * DD + l];
      float w3 = Wc[(k + 3) * DD + l];
      acc0 = fmaf(xv0.x, w0, acc0); acc0 = fmaf(xv0.y, w1, acc0);
      acc0 = fmaf(xv0.z, w2, acc0); acc0 = fmaf(xv0.w, w3, acc0);
      acc1 = fmaf(xv1.x, w0, acc1); acc1 = fmaf(xv1.y, w1, acc1);
      acc1 = fmaf(xv1.z, w2, acc1); acc1 = fmaf(xv1.w, w3, acc1);
    }
  }
  xt[(i0 + r0) * DD + l] = acc0;
  xt[(i0 + r1) * DD + l] = acc1;
  float a1 = a[l], a2 = a[DD + l];
  float p10 = acc0 * a1, p20 = acc0 * a2;
  float p11 = acc1 * a1, p21 = acc1 * a2;
#pragma unroll
  for (int off = 32; off >= 1; off >>= 1) {
    p10 += __shfl_xor(p10, off, 64); p20 += __shfl_xor(p20, off, 64);
    p11 += __shfl_xor(p11, off, 64); p21 += __shfl_xor(p21, off, 64);
  }
  if (l == 0) {
    s1[i0 + r0] = p10; s2[i0 + r0] = p20;
    s1[i0 + r1] = p11; s2[i0 + r1] = p21;
  }
}

// ---------------- kB: rank-by-count + split index --------------------------
// 256 blocks x 256 thr. Block b handles elements/rows b*16..b*16+15:
//  rank of s2[e] among all s2 (stable) -> s2s, perm
//  kidx[i] = #{j : s2[j] <= -s1[i]}  (split point for row i)
__global__ __launch_bounds__(256) void kB_rank(
    const float* __restrict__ s2, const float* __restrict__ s1,
    float* __restrict__ s2s, int* __restrict__ perm, int* __restrict__ kidx) {
  __shared__ float keys[NN];     // 16 KiB
  __shared__ int pc[16][17];
  __shared__ int pk[16][17];
  int tid = threadIdx.x, b = blockIdx.x;
  const float4* s4 = (const float4*)s2;
  float4* kk = (float4*)keys;
#pragma unroll
  for (int u = 0; u < NN / 4 / 256; ++u)
    kk[u * 256 + tid] = s4[u * 256 + tid];
  __syncthreads();
  int el = tid & 15, rep = tid >> 4;
  int e = b * 16 + el;
  float ke = keys[e];
  float te = -s1[e];
  const float4* k4p = (const float4*)keys;
  int cnt = 0, ck = 0;
#pragma unroll 4
  for (int q4 = rep * 64; q4 < rep * 64 + 64; ++q4) {
    float4 kv = k4p[q4];
    int q = q4 * 4;
    cnt += (kv.x < ke || (kv.x == ke && q + 0 < e)) ? 1 : 0;
    cnt += (kv.y < ke || (kv.y == ke && q + 1 < e)) ? 1 : 0;
    cnt += (kv.z < ke || (kv.z == ke && q + 2 < e)) ? 1 : 0;
    cnt += (kv.w < ke || (kv.w == ke && q + 3 < e)) ? 1 : 0;
    ck += (kv.x <= te) ? 1 : 0;
    ck += (kv.y <= te) ? 1 : 0;
    ck += (kv.z <= te) ? 1 : 0;
    ck += (kv.w <= te) ? 1 : 0;
  }
  pc[rep][el] = cnt;
  pk[rep][el] = ck;
  __syncthreads();
  if (tid < 16) {
    int rank = 0, kx = 0;
#pragma unroll
    for (int r = 0; r < 16; ++r) { rank += pc[r][tid]; kx += pk[r][tid]; }
    s2s[rank] = keys[b * 16 + tid];
    perm[rank] = b * 16 + tid;
    kidx[b * 16 + tid] = kx;
  }
}

// ---------------- kC: hierarchical sums (chunk/seg/block) + exp pairs --------
// 8 blocks x 512 thr (8 waves). Block B owns sorted rows [B*512, B*512+512).
// Wave w owns seg s = B*8+w (64 rows = 8 chunks of 8).
__global__ __launch_bounds__(512) void kC_sums(
    const float* __restrict__ xt, const float* __restrict__ s2s,
    const int* __restrict__ perm,
    float2* __restrict__ EPN,
    float* __restrict__ CSP, float* __restrict__ CSN, float2* __restrict__ CZ,
    float* __restrict__ SGP, float* __restrict__ SGN, float2* __restrict__ SZ,
    float* __restrict__ BSP, float* __restrict__ BSN, float2* __restrict__ BZ) {
  __shared__ float2 evL[512];        // per-row (eP,eN) for the block's rows
  __shared__ float segPL[8][64], segNL[8][64];
  __shared__ float2 szL[8];
  int tid = threadIdx.x, w = tid >> 6, l = tid & 63, B = blockIdx.x;
  int segBase = B * 512 + w * 64;    // first sorted row of this wave's seg
  int seg = B * 8 + w;

  // per-row exp pair (lane-parallel: one row per lane)
  int row = segBase + l;
  float key = s2s[row];
  float eP = expf(key);
  float eN = expf(SLOPE * key);
  EPN[row] = make_float2(eP, eN);
  evL[w * 64 + l] = make_float2(eP, eN);
  int pmv = perm[row];               // this lane's row's source index

  // Z sums via shfl-xor tree: chunk level (width 8), then seg level
  float zp = eP, zn = eN;
#pragma unroll
  for (int off = 1; off <= 4; off <<= 1) {
    zp += __shfl_xor(zp, off, 64);
    zn += __shfl_xor(zn, off, 64);
  }
  if ((l & 7) == 0) CZ[seg * 8 + (l >> 3)] = make_float2(zp, zn);
#pragma unroll
  for (int off = 8; off <= 32; off <<= 1) {
    zp += __shfl_xor(zp, off, 64);
    zn += __shfl_xor(zn, off, 64);
  }
  if (l == 0) { SZ[seg] = make_float2(zp, zn); szL[w] = make_float2(zp, zn); }

  // chunk sums (vector, lane = dim d); seg accumulation
  float segP = 0.f, segN = 0.f;
#pragma unroll
  for (int c = 0; c < 8; ++c) {
    float cP = 0.f, cN = 0.f;
#pragma unroll
    for (int rr = 0; rr < 8; ++rr) {
      int pm = __shfl(pmv, c * 8 + rr, 64);
      float xv = xt[pm * DD + l];
      float2 ev = evL[w * 64 + c * 8 + rr];
      cP = fmaf(ev.x, xv, cP);
      cN = fmaf(ev.y, xv, cN);
    }
    CSP[(seg * 8 + c) * DD + l] = cP;
    CSN[(seg * 8 + c) * DD + l] = cN;
    segP += cP; segN += cN;
  }
  SGP[seg * DD + l] = segP;
  SGN[seg * DD + l] = segN;
  segPL[w][l] = segP; segNL[w][l] = segN;
  __syncthreads();

  // block totals (wave 0)
  if (w == 0) {
    float bP = 0.f, bN = 0.f;
#pragma unroll
    for (int s = 0; s < 8; ++s) { bP += segPL[s][l]; bN += segNL[s][l]; }
    BSP[B * DD + l] = bP;
    BSN[B * DD + l] = bN;
    if (l == 0) {
      float2 bz = make_float2(0.f, 0.f);
#pragma unroll
      for (int s = 0; s < 8; ++s) { bz.x += szL[s].x; bz.y += szL[s].y; }
      BZ[B] = bz;
    }
  }
}

// ---------------- kD: per-row output from hierarchical partials --------------
// 256 blocks x 256 thr; 4 rows per wave (lane = dim d).
__global__ __launch_bounds__(256) void kD_out(
    const float* __restrict__ xt, const float* __restrict__ s1,
    const int* __restrict__ perm, const int* __restrict__ kidx,
    const float2* __restrict__ EPN,
    const float* __restrict__ CSP, const float* __restrict__ CSN,
    const float2* __restrict__ CZ,
    const float* __restrict__ SGP, const float* __restrict__ SGN,
    const float2* __restrict__ SZ,
    const float* __restrict__ BSP, const float* __restrict__ BSN,
    const float2* __restrict__ BZ,
    float* __restrict__ out) {
  int tid = threadIdx.x, w = tid >> 6, l = tid & 63, b = blockIdx.x;
  int i = b * 16 + w * 4 + (l & 3);
  float s1v = s1[i];
  int kq = kidx[i];

  // grand totals (P side only needed)
  float totP = 0.f, totZ = 0.f;
#pragma unroll
  for (int j = 0; j < 8; ++j) {
    totP += BSP[j * DD + l];
    totZ += BZ[j].x;
  }

#pragma unroll
  for (int q = 0; q < 4; ++q) {
    int kk_ = __shfl(kq, q, 64);
    float s1q = __shfl(s1v, q, 64);
    float wP = expf(s1q);
    float wN = expf(SLOPE * s1q);
    float FPk = 0.f, FNk = 0.f, ZPk = 0.f, ZNk = 0.f;
    if (kk_ > 0) {
      int r = kk_ - 1;
      int br = r >> 9, sr = (r >> 6) & 7, cr = (r >> 3) & 7;
      int segg = r >> 6, base = r & ~7, rlim = r & 7;
      // full blocks below
#pragma unroll
      for (int j = 0; j < 7; ++j) {
        float vP = BSP[j * DD + l], vN = BSN[j * DD + l];
        float2 z = BZ[j];
        bool p = j < br;
        FPk += p ? vP : 0.f; FNk += p ? vN : 0.f;
        ZPk += p ? z.x : 0.f; ZNk += p ? z.y : 0.f;
      }
      // full segs below within block br
#pragma unroll
      for (int j = 0; j < 7; ++j) {
        int idx = (br << 3) + j;
        float vP = SGP[idx * DD + l], vN = SGN[idx * DD + l];
        float2 z = SZ[idx];
        bool p = j < sr;
        FPk += p ? vP : 0.f; FNk += p ? vN : 0.f;
        ZPk += p ? z.x : 0.f; ZNk += p ? z.y : 0.f;
      }
      // full chunks below within seg
#pragma unroll
      for (int j = 0; j < 7; ++j) {
        int idx = (segg << 3) + j;
        float vP = CSP[idx * DD + l], vN = CSN[idx * DD + l];
        float2 z = CZ[idx];
        bool p = j < cr;
        FPk += p ? vP : 0.f; FNk += p ? vN : 0.f;
        ZPk += p ? z.x : 0.f; ZNk += p ? z.y : 0.f;
      }
      // rows within chunk
#pragma unroll
      for (int j = 0; j < 8; ++j) {
        int rw = base + j;
        float2 ev = EPN[rw];
        int pm = perm[rw];
        float xv = xt[pm * DD + l];
        bool p = j <= rlim;
        FPk = fmaf(p ? ev.x : 0.f, xv, FPk);
        FNk = fmaf(p ? ev.y : 0.f, xv, FNk);
        ZPk += p ? ev.x : 0.f; ZNk += p ? ev.y : 0.f;
      }
    }
    float num = wP * (totP - FPk) + wN * FNk;
    float den = wP * (totZ - ZPk) + wN * ZNk;
    out[(b * 16 + w * 4 + q) * DD + l] = num / den;
  }
}

extern "C" void kernel_launch(void* const* d_in, const int* in_sizes, int n_in,
                              void* d_out, int out_size, void* d_ws, size_t ws_size,
                              hipStream_t stream) {
  const float* x = (const float*)d_in[0];
  const float* W = (const float*)d_in[1];
  const float* a = (const float*)d_in[2];
  float* out = (float*)d_out;

  float* ws = (float*)d_ws;
  float*  xt   = ws;                     // 262144
  float*  s1   = xt + NN * DD;           // 4096
  float*  s2   = s1 + NN;                // 4096
  float*  s2s  = s2 + NN;                // 4096
  int*    perm = (int*)(s2s + NN);       // 4096
  int*    kidx = perm + NN;              // 4096
  float2* EPN  = (float2*)(kidx + NN);   // 4096 float2
  float*  CSP  = (float*)(EPN + NN);     // 512*64
  float*  CSN  = CSP + NCHUNK * DD;      // 512*64
  float2* CZ   = (float2*)(CSN + NCHUNK * DD);   // 512 float2
  float*  SGP  = (float*)(CZ + NCHUNK);  // 64*64
  float*  SGN  = SGP + NSEG * DD;        // 64*64
  float2* SZ   = (float2*)(SGN + NSEG * DD);     // 64 float2
  float*  BSP  = (float*)(SZ + NSEG);    // 8*64
  float*  BSN  = BSP + NBLK8 * DD;       // 8*64
  float2* BZ   = (float2*)(BSN + NBLK8 * DD);    // 8 float2

  kA_xt<<<NN / 8, 256, 0, stream>>>(x, W, a, xt, s1, s2);
  kB_rank<<<NN / 16, 256, 0, stream>>>(s2, s1, s2s, perm, kidx);
  kC_sums<<<NBLK8, 512, 0, stream>>>(xt, s2s, perm, EPN, CSP, CSN, CZ,
                                     SGP, SGN, SZ, BSP, BSN, BZ);
  kD_out<<<NN / 16, 256, 0, stream>>>(xt, s1, perm, kidx, EPN, CSP, CSN, CZ,
                                      SGP, SGN, SZ, BSP, BSN, BZ, out);
}